// Round 5
// baseline (377.550 us; speedup 1.0000x reference)
//
#include <hip/hip_runtime.h>
#include <math.h>

#define N_TOTAL    68096
#define NUM_INPUT  2048
#define NUM_OUTPUT 512
#define OUT_START  67584   // NUM_INPUT + NUM_HIDDEN
#define N_TGT      66048   // N_TOTAL - NUM_INPUT
#define FAN_OUT    256
#define THRESH     0.3f
#define T_MAX      50
#define T_BIG      10      // steps [0, T_BIG) multi-launch; rest in tail_k
#define BM_WORDS   2064    // ceil(66048 / 32)
#define LIST_CAP   12288

#define HALF_SZ    33024   // N_TGT / 2
#define N_CHUNK    128     // max frontier chunks in dense mode
#define DENSE_THR  2000    // frontier size at/above which dense path engages

// ---------------------------------------------------------------------------
// init: decay table, state arrays, frontier0 from input spikes.
// Input-bool dtype (int32/float32/uint8) detected per-block (2 KB scan).
// ---------------------------------------------------------------------------
__global__ __launch_bounds__(256) void init_k(
    const unsigned int* __restrict__ in0,
    float* pot, float* acc, int* last_up, unsigned char* fired,
    int* frontier0, int* cnt, float* out_f, float* decay_tab)
{
    __shared__ int sF, sG;
    const int tid = threadIdx.x;
    if (tid == 0) { sF = 0; sG = 0; }
    __syncthreads();
    for (int k = tid; k < 512; k += 256) {       // 2048 bytes: safe all modes
        unsigned int v = in0[k];
        if (v == 0x3F800000u) atomicAdd(&sF, 1);
        else if (v > 1u)      sG = 1;            // benign race
    }
    __syncthreads();
    const int mode = (sF >= 8) ? 1 : (sG ? 2 : 0);

    const int i = blockIdx.x * 256 + tid;
    const int lane = tid & 63;
    if (i <= T_MAX) {
        float base = expf(-0.05f);               // exact validated path
        decay_tab[i] = (float)pow((double)base, (double)i);
    }
    if (i < NUM_OUTPUT) out_f[i] = -1.0f;
    bool want = false;
    if (i < N_TOTAL) {
        pot[i] = 0.0f;
        acc[i] = 0.0f;
        last_up[i] = 0;
        bool s = false;
        if (i < NUM_INPUT) {
            if (mode == 0)      s = ((const int*)in0)[i] != 0;
            else if (mode == 1) s = ((const float*)in0)[i] != 0.0f;
            else                s = ((const unsigned char*)in0)[i] != 0;
        }
        fired[i] = s ? 1 : 0;
        want = s;
    }
    unsigned long long m = __ballot(want);
    if (m) {
        int leader = __ffsll((long long)m) - 1;
        int base = 0;
        if (lane == leader) base = atomicAdd(&cnt[0], __popcll(m));
        base = __shfl(base, leader, 64);
        if (want) {
            int off = __popcll(m & ((1ull << (unsigned)lane) - 1ull));
            frontier0[base + off] = i;
        }
    }
}

// ---------------------------------------------------------------------------
// per-step scatter, path chosen on device:
//   fcnt <  DENSE_THR : device atomics into acc (sparse)
//   fcnt >= DENSE_THR : block (chunk c, half h) accumulates its chunk's
//     in-range edges in 132 KB LDS (LDS atomics), writes partial to
//     rep[(c*2+h)][.] with plain stores. chunks adaptive = clamp(fcnt/128).
// ---------------------------------------------------------------------------
__global__ __launch_bounds__(1024) void step_scatter_k(
    const int* __restrict__ fr, const int* __restrict__ cnt_cur,
    int* cnt_next,
    const int* __restrict__ targets, const float* __restrict__ weights,
    float* __restrict__ acc, float* __restrict__ rep)
{
    __shared__ float lacc[HALF_SZ];              // 132 KB (static)
    const int fcnt = *cnt_cur;
    const int tid  = threadIdx.x;
    if (blockIdx.x == 0 && tid == 0) *cnt_next = 0;
    if (fcnt == 0) return;

    if (fcnt < DENSE_THR) {
        // ---- sparse path ----
        const int nq = fcnt * (FAN_OUT / 4);
        const int stride = gridDim.x * 1024;
        for (int q = blockIdx.x * 1024 + tid; q < nq; q += stride) {
            int s  = fr[q >> 6];                 // wave-uniform source
            int j4 = (q & 63) << 2;
            const int base = s * FAN_OUT + j4;
            int4   tg = *(const int4*)  (targets + base);
            float4 wv = *(const float4*)(weights + base);
            float  st = (s < NUM_INPUT) ? 2.0f : 1.0f;
            atomicAdd(&acc[tg.x], st * wv.x);
            atomicAdd(&acc[tg.y], st * wv.y);
            atomicAdd(&acc[tg.z], st * wv.z);
            atomicAdd(&acc[tg.w], st * wv.w);
        }
        return;
    }

    // ---- dense path ----
    int chunks = fcnt >> 7;                      // ~128 sources per chunk
    if (chunks > N_CHUNK) chunks = N_CHUNK;
    const int c = blockIdx.x >> 1;
    if (c >= chunks) return;
    const int h    = blockIdx.x & 1;
    const int base = NUM_INPUT + h * HALF_SZ;
    for (int k = tid; k < HALF_SZ / 4; k += 1024)
        ((float4*)lacc)[k] = make_float4(0.f, 0.f, 0.f, 0.f);
    __syncthreads();
    const int lo = (int)(((long long)fcnt * c)       / chunks);
    const int hi = (int)(((long long)fcnt * (c + 1)) / chunks);
    const int nq = (hi - lo) << 6;
    for (int q = tid; q < nq; q += 1024) {
        const int s  = fr[lo + (q >> 6)];        // wave-uniform source
        const int j4 = (q & 63) << 2;
        const int eb = s * FAN_OUT + j4;
        int4   tg = *(const int4*)  (targets + eb);
        float4 wv = *(const float4*)(weights + eb);
        float  st = (s < NUM_INPUT) ? 2.0f : 1.0f;
        int x;
        x = tg.x - base; if ((unsigned)x < HALF_SZ) atomicAdd(&lacc[x], st * wv.x);
        x = tg.y - base; if ((unsigned)x < HALF_SZ) atomicAdd(&lacc[x], st * wv.y);
        x = tg.z - base; if ((unsigned)x < HALF_SZ) atomicAdd(&lacc[x], st * wv.z);
        x = tg.w - base; if ((unsigned)x < HALF_SZ) atomicAdd(&lacc[x], st * wv.w);
    }
    __syncthreads();
    float4* out = (float4*)(rep + (size_t)((c << 1) + h) * HALF_SZ);
    for (int k = tid; k < HALF_SZ / 4; k += 1024) out[k] = ((float4*)lacc)[k];
}

// ---------------------------------------------------------------------------
// per-step update, same path condition: gather acc (sparse) or reduce the
// chunks partials (dense), then identical decay/fire/frontier logic.
// ---------------------------------------------------------------------------
__global__ __launch_bounds__(1024) void step_update_k(
    const float* __restrict__ rep, const int* __restrict__ cnt_cur,
    float* __restrict__ pot, float* __restrict__ acc,
    int* __restrict__ last_up, unsigned char* __restrict__ fired,
    int* __restrict__ frontier_next, int* __restrict__ cnt_next,
    float* __restrict__ out_f, const float* __restrict__ decay_tab, int t)
{
    const int fcnt = *cnt_cur;
    if (fcnt == 0) return;
    const int g = blockIdx.x * 1024 + threadIdx.x;   // 0 .. 66559
    const int lane = threadIdx.x & 63;
    bool w2 = false;
    const int n = NUM_INPUT + g;
    if (g < N_TGT) {
        float a = 0.0f;
        if (fcnt < DENSE_THR) {
            a = acc[n];
            if (a != 0.0f) acc[n] = 0.0f;
        } else {
            int chunks = fcnt >> 7;
            if (chunks > N_CHUNK) chunks = N_CHUNK;
            const int hh  = (g >= HALF_SZ) ? 1 : 0;
            const int idx = g - hh * HALF_SZ;
            const float* p0 = rep + (size_t)hh * HALF_SZ + idx;
            for (int c = 0; c < chunks; ++c)
                a += p0[(size_t)(c << 1) * HALF_SZ];
        }
        if (a != 0.0f) {
            float p = pot[n] * decay_tab[t - last_up[n]] + a;
            last_up[n] = t;
            if (!fired[n] && p >= THRESH) {
                fired[n] = 1;
                if (n < OUT_START) { p = 0.0f; w2 = true; }
                else out_f[n - OUT_START] = (float)t;
            }
            pot[n] = p;
        }
    }
    unsigned long long m = __ballot(w2);
    if (m) {
        int leader = __ffsll((long long)m) - 1;
        int base = 0;
        if (lane == leader) base = atomicAdd(cnt_next, __popcll(m));
        base = __shfl(base, leader, 64);
        if (w2) {
            int off = __popcll(m & ((1ull << (unsigned)lane) - 1ull));
            frontier_next[base + off] = n;
        }
    }
}

// ---------------------------------------------------------------------------
// tail: one workgroup runs steps [T_BIG, 50), __syncthreads barriers,
// LDS-bitmap touched-list, early exit; writes final out_pot.
// ---------------------------------------------------------------------------
__global__ __launch_bounds__(1024) void tail_k(
    float* __restrict__ pot, float* __restrict__ acc,
    int* __restrict__ last_up, unsigned char* __restrict__ fired,
    int* __restrict__ fr0, int* __restrict__ fr1, int* __restrict__ cnt,
    const int* __restrict__ targets, const float* __restrict__ weights,
    float* __restrict__ out_f, const float* __restrict__ decay_tab)
{
    __shared__ unsigned bm[BM_WORDS];
    __shared__ int      lst[LIST_CAP];
    __shared__ int      lcnt, ovf;
    __shared__ float    sdecay[T_MAX + 1];
    const int tid = threadIdx.x;
    if (tid <= T_MAX) sdecay[tid] = decay_tab[tid];

    for (int t = T_BIG; t < T_MAX; ++t) {
        const int cur = t & 1, nxt = cur ^ 1;
        for (int k = tid; k < BM_WORDS; k += 1024) bm[k] = 0u;
        if (tid == 0) { lcnt = 0; ovf = 0; cnt[nxt] = 0; }
        __syncthreads();
        const int fcnt = cnt[cur];
        if (fcnt == 0) break;
        const int* fr  = (cur == 0) ? fr0 : fr1;
        int*       frn = (cur == 0) ? fr1 : fr0;

        const int nq = fcnt * (FAN_OUT / 4);
        for (int q = tid; q < nq; q += 1024) {
            int s  = fr[q >> 6];
            int j4 = (q & 63) << 2;
            const int base = s * FAN_OUT + j4;
            int4   tg = *(const int4*)  (targets + base);
            float4 wv = *(const float4*)(weights + base);
            float  st = (s < NUM_INPUT) ? 2.0f : 1.0f;
            #define EDGE(TG, WV) do {                                         \
                atomicAdd(&acc[TG], st * (WV));                               \
                int b = (TG) - NUM_INPUT;                                     \
                unsigned bit = 1u << (b & 31);                                \
                unsigned old = atomicOr(&bm[b >> 5], bit);                    \
                if (!(old & bit)) {                                           \
                    int p_ = atomicAdd(&lcnt, 1);                             \
                    if (p_ < LIST_CAP) lst[p_] = (TG); else ovf = 1;          \
                } } while (0)
            EDGE(tg.x, wv.x); EDGE(tg.y, wv.y);
            EDGE(tg.z, wv.z); EDGE(tg.w, wv.w);
            #undef EDGE
        }
        __syncthreads();

        const int M = lcnt;
        const bool full = (ovf != 0);
        const int lo = full ? (NUM_INPUT + tid) : tid;
        const int hi = full ? N_TOTAL : M;
        for (int k = lo; k < hi; k += 1024) {
            const int n = full ? k : lst[k];
            float a = __hip_atomic_load(&acc[n], __ATOMIC_RELAXED,
                                        __HIP_MEMORY_SCOPE_AGENT);
            if (a != 0.0f) {
                __hip_atomic_store(&acc[n], 0.0f, __ATOMIC_RELAXED,
                                   __HIP_MEMORY_SCOPE_AGENT);
                float p = pot[n] * sdecay[t - last_up[n]] + a;
                last_up[n] = t;
                if (!fired[n] && p >= THRESH) {
                    fired[n] = 1;
                    if (n < OUT_START) {
                        p = 0.0f;
                        int pos = atomicAdd(&cnt[nxt], 1);
                        frn[pos] = n;
                    } else out_f[n - OUT_START] = (float)t;
                }
                pot[n] = p;
            }
        }
        __syncthreads();
    }

    __syncthreads();
    for (int i = tid; i < NUM_OUTPUT; i += 1024) {
        int n = OUT_START + i;
        out_f[NUM_OUTPUT + i] = pot[n] * sdecay[T_MAX - last_up[n]];
    }
}

extern "C" void kernel_launch(void* const* d_in, const int* in_sizes, int n_in,
                              void* d_out, int out_size, void* d_ws, size_t ws_size,
                              hipStream_t stream) {
    const void*  in_spikes = d_in[0];
    const float* weights   = (const float*)d_in[1];
    const int*   targets   = (const int*)d_in[2];
    float*       out_f     = (float*)d_out;

    char* w = (char*)d_ws;
    int*   cnt       = (int*)w;                  // [0],[1] frontier counts
    float* decay_tab = (float*)(w + 256);        // 51 floats
    float* pot       = (float*)(w + 512);
    float* acc       = pot + N_TOTAL;
    int*   last_up   = (int*)(acc + N_TOTAL);
    int*   fr0       = last_up + N_TOTAL;
    int*   fr1       = fr0 + N_TOTAL;
    unsigned char* fired = (unsigned char*)(fr1 + N_TOTAL);
    size_t base_bytes = (size_t)((char*)(fired + N_TOTAL) - w);
    size_t rep_off    = (base_bytes + 255) & ~(size_t)255;
    float* rep        = (float*)(w + rep_off);

    hipMemsetAsync(cnt, 0, 16, stream);
    init_k<<<266, 256, 0, stream>>>((const unsigned int*)in_spikes,
                                    pot, acc, last_up, fired,
                                    fr0, cnt, out_f, decay_tab);

    int* fr[2] = {fr0, fr1};
    for (int t = 0; t < T_BIG; ++t) {
        const int cur = t & 1, nxt = cur ^ 1;
        step_scatter_k<<<2 * N_CHUNK, 1024, 0, stream>>>(
            fr[cur], &cnt[cur], &cnt[nxt], targets, weights, acc, rep);
        step_update_k<<<65, 1024, 0, stream>>>(
            rep, &cnt[cur], pot, acc, last_up, fired,
            fr[nxt], &cnt[nxt], out_f, decay_tab, t);
    }
    tail_k<<<1, 1024, 0, stream>>>(pot, acc, last_up, fired, fr0, fr1, cnt,
                                   targets, weights, out_f, decay_tab);
}